// Round 17
// baseline (204.357 us; speedup 1.0000x reference)
//
#include <hip/hip_runtime.h>
#include <hip/hip_bf16.h>
#include <math.h>

#define IN_DIM 256
#define HIDDEN 256
#define HEADS 8
#define FPH 32
#define NCLS 40

typedef __attribute__((ext_vector_type(8))) short bf16x8;
typedef __attribute__((ext_vector_type(4))) float f32x4;

__device__ inline unsigned short f2bf(float f) {
    unsigned int u = __float_as_uint(f);
    unsigned int r = (u + 0x7FFF + ((u >> 16) & 1)) >> 16;
    return (unsigned short)r;
}
__device__ inline float bf2f(unsigned short u) {
    return __uint_as_float(((unsigned int)u) << 16);
}

// ---------------- histprep: hist (blocks < nhist) || prep (LDS-free union) ----------------
__global__ void histprep_kernel(const int* __restrict__ dst, int* __restrict__ deg,
                                int* __restrict__ rank, int E,
                                const float* __restrict__ W1, const float* __restrict__ W2,
                                const float* __restrict__ a_src1, const float* __restrict__ a_dst1,
                                const float* __restrict__ a_src2, const float* __restrict__ a_dst2,
                                unsigned short* __restrict__ W1tb, unsigned short* __restrict__ W2tb,
                                unsigned short* __restrict__ Aw, int nhist) {
    int bid = blockIdx.x;
    int tid = threadIdx.x;
    if (bid < nhist) {
        int e = bid * 256 + tid;
        if (e < E) rank[e] = atomicAdd(&deg[dst[e]], 1);
        return;
    }
    int pbid = bid - nhist;
    if (pbid < 256) {
        int k = pbid, j = tid;
        float w = W1[(size_t)k * 256 + j];
        W1tb[(size_t)j * 256 + k] = f2bf(w);
        float s = w * a_src1[j];
        float d = w * a_dst1[j];
#pragma unroll
        for (int m = 1; m < 32; m <<= 1) {
            s += __shfl_xor(s, m, 64);
            d += __shfl_xor(d, m, 64);
        }
        if ((j & 31) == 0) {
            int hd = j >> 5;
            Aw[(size_t)(2 * hd) * 256 + k]     = f2bf(s);
            Aw[(size_t)(2 * hd + 1) * 256 + k] = f2bf(d);
        }
    } else {
        int c = pbid - 256;  // 0..63
        if (c < NCLS) {
            W2tb[(size_t)c * 256 + tid] = f2bf(W2[(size_t)tid * NCLS + c]);
        } else if (c == 48 || c == 49) {
            const float* aptr = (c == 48) ? a_src2 : a_dst2;
            const float* wr = &W2[(size_t)tid * NCLS];
            float s = 0.f;
#pragma unroll
            for (int f = 0; f < NCLS; f++) s += wr[f] * aptr[f];
            W2tb[(size_t)c * 256 + tid] = f2bf(s);
        } else {
            W2tb[(size_t)c * 256 + tid] = 0;
        }
    }
}

__global__ __launch_bounds__(1024) void scan_blocks_kernel(const int* __restrict__ deg,
                                                           int* __restrict__ excl,
                                                           int* __restrict__ bsum, int N) {
    __shared__ int sm[1024];
    int t = threadIdx.x;
    int g = blockIdx.x * 1024 + t;
    int v = (g < N) ? deg[g] : 0;
    sm[t] = v;
    __syncthreads();
    for (int o = 1; o < 1024; o <<= 1) {
        int add = (t >= o) ? sm[t - o] : 0;
        __syncthreads();
        sm[t] += add;
        __syncthreads();
    }
    if (g < N) excl[g] = sm[t] - v;
    if (t == 1023) bsum[blockIdx.x] = sm[1023];
}

__global__ void add_base_kernel(const int* __restrict__ excl, const int* __restrict__ bsum,
                                int* __restrict__ offs, int N, int nb) {
    int g = blockIdx.x * blockDim.x + threadIdx.x;
    if (g > N) return;
    int nblk = g >> 10;
    int lim = (g == N) ? nb : nblk;
    int base = 0;
    for (int i = 0; i < lim; i++) base += bsum[i];
    if (g < N) {
        offs[g] = excl[g] + base;
    } else {
        offs[N] = base;
    }
}

__global__ void fill_kernel(const int* __restrict__ src, const int* __restrict__ dst,
                            const int* __restrict__ rank, const int* __restrict__ offs,
                            int* __restrict__ adjsrc, int E) {
    int e = blockIdx.x * blockDim.x + threadIdx.x;
    if (e < E) {
        int d = dst[e];
        adjsrc[offs[d] + rank[e]] = src[e];
    }
}

// ---------------- GEMM1 MFMA + fused alpha1: 128 rows/block, 512 threads (8 waves) ----------------
__global__ __launch_bounds__(512) void gemm1_mfma(const float* __restrict__ A,
                                                  const unsigned short* __restrict__ Btb,
                                                  const unsigned short* __restrict__ Aw,
                                                  unsigned short* __restrict__ Cb,
                                                  float* __restrict__ as_o,
                                                  float* __restrict__ ad_o, int M) {
    __shared__ unsigned short smem[16896];  // K-loop: 128*40 + 256*40 + 16*40 = 16000; epi: Co 64*264=16896
    unsigned short* As = smem;               // [128][40]
    unsigned short* Bs = smem + 128 * 40;    // [256][40]
    unsigned short* Bsa = smem + 128 * 40 + 256 * 40;  // [16][40]
    int t = threadIdx.x;
    int wave = t >> 6, lane = t & 63;
    int rowBase = blockIdx.x * 128;
    int lrow = lane & 15, lk = (lane >> 4) * 8;
    f32x4 acc[16] = {};
    f32x4 acca = {};
    int arow = t >> 2, akq = (t & 3) * 8;
    int bcol = t >> 1, bh = (t & 1) * 16;
    for (int k0 = 0; k0 < 256; k0 += 32) {
        int grow = rowBase + arow;
        float4 a0 = {0.f, 0.f, 0.f, 0.f}, a1 = {0.f, 0.f, 0.f, 0.f};
        if (grow < M) {
            a0 = *reinterpret_cast<const float4*>(&A[(size_t)grow * 256 + k0 + akq]);
            a1 = *reinterpret_cast<const float4*>(&A[(size_t)grow * 256 + k0 + akq + 4]);
        }
        ushort4 p0 = {f2bf(a0.x), f2bf(a0.y), f2bf(a0.z), f2bf(a0.w)};
        ushort4 p1 = {f2bf(a1.x), f2bf(a1.y), f2bf(a1.z), f2bf(a1.w)};
        *reinterpret_cast<ushort4*>(&As[arow * 40 + akq]) = p0;
        *reinterpret_cast<ushort4*>(&As[arow * 40 + akq + 4]) = p1;
        {
            uint4 bv0 = *reinterpret_cast<const uint4*>(&Btb[(size_t)bcol * 256 + k0 + bh]);
            uint4 bv1 = *reinterpret_cast<const uint4*>(&Btb[(size_t)bcol * 256 + k0 + bh + 8]);
            *reinterpret_cast<uint4*>(&Bs[bcol * 40 + bh]) = bv0;
            *reinterpret_cast<uint4*>(&Bs[bcol * 40 + bh + 8]) = bv1;
        }
        if (t < 16) {
#pragma unroll
            for (int q = 0; q < 4; q++) {
                uint4 av = *reinterpret_cast<const uint4*>(&Aw[(size_t)t * 256 + k0 + q * 8]);
                *reinterpret_cast<uint4*>(&Bsa[t * 40 + q * 8]) = av;
            }
        }
        __syncthreads();
        bf16x8 a = *reinterpret_cast<const bf16x8*>(&As[(wave * 16 + lrow) * 40 + lk]);
#pragma unroll
        for (int j = 0; j < 16; j++) {
            bf16x8 b = *reinterpret_cast<const bf16x8*>(&Bs[(j * 16 + lrow) * 40 + lk]);
            acc[j] = __builtin_amdgcn_mfma_f32_16x16x32_bf16(a, b, acc[j], 0, 0, 0);
        }
        bf16x8 ba = *reinterpret_cast<const bf16x8*>(&Bsa[lrow * 40 + lk]);
        acca = __builtin_amdgcn_mfma_f32_16x16x32_bf16(a, ba, acca, 0, 0, 0);
        __syncthreads();
    }
    int r0 = (lane >> 4) * 4;
    {
        int c = lrow, hd = c >> 1;
        float* dsts = (c & 1) ? ad_o : as_o;
#pragma unroll
        for (int r = 0; r < 4; r++) {
            int row = rowBase + wave * 16 + r0 + r;
            if (row < M) dsts[row * HEADS + hd] = acca[r];
        }
    }
    unsigned short* Co = smem;
#pragma unroll
    for (int h = 0; h < 2; h++) {
        __syncthreads();
        if ((wave >> 2) == h) {
            int lw = wave & 3;
#pragma unroll
            for (int j = 0; j < 16; j++)
#pragma unroll
                for (int r = 0; r < 4; r++)
                    Co[(lw * 16 + r0 + r) * 264 + j * 16 + lrow] = f2bf(acc[j][r]);
        }
        __syncthreads();
        int wrow = t >> 3, wchunk = (t & 7) * 32;
        int row = rowBase + h * 64 + wrow;
        if (row < M) {
#pragma unroll
            for (int q = 0; q < 4; q++) {
                uint4 v = *reinterpret_cast<const uint4*>(&Co[wrow * 264 + wchunk + q * 8]);
                *reinterpret_cast<uint4*>(&Cb[(size_t)row * 256 + wchunk + q * 8]) = v;
            }
        }
    }
}

// ---------------- GEMM2 MFMA + fused alpha2: 128 rows/block, 512 threads ----------------
__global__ __launch_bounds__(512) void gemm2_mfma(const unsigned short* __restrict__ Ab,
                                                  const unsigned short* __restrict__ Btb,
                                                  unsigned short* __restrict__ Cb,
                                                  float* __restrict__ as_o,
                                                  float* __restrict__ ad_o, int M) {
    __shared__ unsigned short As[128 * 40];
    __shared__ unsigned short Bs[64 * 40];
    int t = threadIdx.x;
    int wave = t >> 6, lane = t & 63;
    int rowBase = blockIdx.x * 128;
    int lrow = lane & 15, lk = (lane >> 4) * 8;
    f32x4 acc[4] = {};
    int srow = t >> 2, skq = (t & 3) * 8;
    for (int k0 = 0; k0 < 256; k0 += 32) {
        uint4 av = {0, 0, 0, 0};
        int grow = rowBase + srow;
        if (grow < M) av = *reinterpret_cast<const uint4*>(&Ab[(size_t)grow * 256 + k0 + skq]);
        *reinterpret_cast<uint4*>(&As[srow * 40 + skq]) = av;
        if (t < 256) {
            int brow = t >> 2, bkq = (t & 3) * 8;
            uint4 bv = *reinterpret_cast<const uint4*>(&Btb[(size_t)brow * 256 + k0 + bkq]);
            *reinterpret_cast<uint4*>(&Bs[brow * 40 + bkq]) = bv;
        }
        __syncthreads();
        bf16x8 a = *reinterpret_cast<const bf16x8*>(&As[(wave * 16 + lrow) * 40 + lk]);
#pragma unroll
        for (int j = 0; j < 4; j++) {
            bf16x8 b = *reinterpret_cast<const bf16x8*>(&Bs[(j * 16 + lrow) * 40 + lk]);
            acc[j] = __builtin_amdgcn_mfma_f32_16x16x32_bf16(a, b, acc[j], 0, 0, 0);
        }
        __syncthreads();
    }
    int crow0 = rowBase + wave * 16 + (lane >> 4) * 4;
    int ccol = lane & 15;
#pragma unroll
    for (int j = 0; j < 3; j++)
#pragma unroll
        for (int r = 0; r < 4; r++) {
            int row = crow0 + r;
            if (row < M) Cb[(size_t)row * 48 + j * 16 + ccol] = f2bf(acc[j][r]);
        }
    if (ccol < 2) {
        float* dsts = ccol ? ad_o : as_o;
#pragma unroll
        for (int r = 0; r < 4; r++) {
            int row = crow0 + r;
            if (row < M) dsts[row] = acc[3][r];
        }
    }
}

// ---------------- aggregation layer 1: one wave per node, 8-deep pipelined gather ----------------
__global__ __launch_bounds__(256) void agg1_kernel(const unsigned short* __restrict__ h1b,
                                                   const float* __restrict__ as,
                                                   const float* __restrict__ ad,
                                                   const int* __restrict__ offs,
                                                   const int* __restrict__ adjsrc,
                                                   const float* __restrict__ b,
                                                   unsigned short* __restrict__ outb, int N) {
    int wid = (blockIdx.x * blockDim.x + threadIdx.x) >> 6;
    int lane = threadIdx.x & 63;
    if (wid >= N) return;
    int n = wid;
    int hd = lane >> 3;
    int beg = offs[n], end = offs[n + 1];
    float adh = ad[n * HEADS + hd];
    float ssum = 0.f;
    float4 acc = {0.f, 0.f, 0.f, 0.f};
    int i = beg;
    for (; i + 8 <= end; i += 8) {
        int sidx[8];
        float av[8];
        ushort4 hv[8];
#pragma unroll
        for (int u = 0; u < 8; u++) sidx[u] = adjsrc[i + u];
#pragma unroll
        for (int u = 0; u < 8; u++) av[u] = as[sidx[u] * HEADS + hd];
#pragma unroll
        for (int u = 0; u < 8; u++)
            hv[u] = *reinterpret_cast<const ushort4*>(&h1b[(size_t)sidx[u] * HIDDEN + lane * 4]);
#pragma unroll
        for (int u = 0; u < 8; u++) {
            float e = av[u] + adh;
            e = e > 0.f ? e : 0.2f * e;
            float ex = __expf(e);
            ssum += ex;
            acc.x += ex * bf2f(hv[u].x);
            acc.y += ex * bf2f(hv[u].y);
            acc.z += ex * bf2f(hv[u].z);
            acc.w += ex * bf2f(hv[u].w);
        }
    }
    for (; i + 4 <= end; i += 4) {
        int sidx[4];
        float av[4];
        ushort4 hv[4];
#pragma unroll
        for (int u = 0; u < 4; u++) sidx[u] = adjsrc[i + u];
#pragma unroll
        for (int u = 0; u < 4; u++) av[u] = as[sidx[u] * HEADS + hd];
#pragma unroll
        for (int u = 0; u < 4; u++)
            hv[u] = *reinterpret_cast<const ushort4*>(&h1b[(size_t)sidx[u] * HIDDEN + lane * 4]);
#pragma unroll
        for (int u = 0; u < 4; u++) {
            float e = av[u] + adh;
            e = e > 0.f ? e : 0.2f * e;
            float ex = __expf(e);
            ssum += ex;
            acc.x += ex * bf2f(hv[u].x);
            acc.y += ex * bf2f(hv[u].y);
            acc.z += ex * bf2f(hv[u].z);
            acc.w += ex * bf2f(hv[u].w);
        }
    }
    for (; i < end; i++) {
        int s = adjsrc[i];
        float e = as[s * HEADS + hd] + adh;
        e = e > 0.f ? e : 0.2f * e;
        float ex = __expf(e);
        ssum += ex;
        ushort4 hv = *reinterpret_cast<const ushort4*>(&h1b[(size_t)s * HIDDEN + lane * 4]);
        acc.x += ex * bf2f(hv.x);
        acc.y += ex * bf2f(hv.y);
        acc.z += ex * bf2f(hv.z);
        acc.w += ex * bf2f(hv.w);
    }
    float inv = 1.f / (ssum + 1e-16f);
    int col = lane * 4;
    float4 o;
    o.x = acc.x * inv + b[col + 0];
    o.y = acc.y * inv + b[col + 1];
    o.z = acc.z * inv + b[col + 2];
    o.w = acc.w * inv + b[col + 3];
    o.x = o.x > 0.f ? o.x : expm1f(o.x);
    o.y = o.y > 0.f ? o.y : expm1f(o.y);
    o.z = o.z > 0.f ? o.z : expm1f(o.z);
    o.w = o.w > 0.f ? o.w : expm1f(o.w);
    ushort4 ob;
    ob.x = f2bf(o.x); ob.y = f2bf(o.y); ob.z = f2bf(o.z); ob.w = f2bf(o.w);
    *reinterpret_cast<ushort4*>(&outb[(size_t)n * HIDDEN + col]) = ob;
}

// ---------------- aggregation layer 2: half-wave, 16 edges/iter (8 gathers/half in flight) ----------------
__global__ __launch_bounds__(256) void agg2_kernel(const unsigned short* __restrict__ h2b,
                                                   const float* __restrict__ as,
                                                   const float* __restrict__ ad,
                                                   const int* __restrict__ offs,
                                                   const int* __restrict__ adjsrc,
                                                   const float* __restrict__ b,
                                                   float* __restrict__ out, int N) {
    int wid = (blockIdx.x * blockDim.x + threadIdx.x) >> 6;
    int lane = threadIdx.x & 63;
    if (wid >= N) return;
    int n = wid;
    int half = lane >> 5;
    int l = lane & 31;
    bool act = l < 20;
    int beg = offs[n], end = offs[n + 1];
    float adh = ad[n];
    float ssum = 0.f;
    float acc0 = 0.f, acc1 = 0.f;
    int i = beg;
    for (; i + 16 <= end; i += 16) {
        int sidx[8];
        float av[8];
        unsigned int hv[8];
#pragma unroll
        for (int u = 0; u < 8; u++) sidx[u] = adjsrc[i + 2 * u + half];
#pragma unroll
        for (int u = 0; u < 8; u++) av[u] = as[sidx[u]];
#pragma unroll
        for (int u = 0; u < 8; u++)
            hv[u] = act ? *reinterpret_cast<const unsigned int*>(&h2b[(size_t)sidx[u] * 48 + l * 2]) : 0u;
#pragma unroll
        for (int u = 0; u < 8; u++) {
            float e = av[u] + adh;
            e = e > 0.f ? e : 0.2f * e;
            float ex = __expf(e);
            ssum += ex;
            acc0 += ex * __uint_as_float(hv[u] << 16);
            acc1 += ex * __uint_as_float(hv[u] & 0xffff0000u);
        }
    }
    for (; i + 8 <= end; i += 8) {
        int sidx[4];
        float av[4];
        unsigned int hv[4];
#pragma unroll
        for (int u = 0; u < 4; u++) sidx[u] = adjsrc[i + 2 * u + half];
#pragma unroll
        for (int u = 0; u < 4; u++) av[u] = as[sidx[u]];
#pragma unroll
        for (int u = 0; u < 4; u++)
            hv[u] = act ? *reinterpret_cast<const unsigned int*>(&h2b[(size_t)sidx[u] * 48 + l * 2]) : 0u;
#pragma unroll
        for (int u = 0; u < 4; u++) {
            float e = av[u] + adh;
            e = e > 0.f ? e : 0.2f * e;
            float ex = __expf(e);
            ssum += ex;
            acc0 += ex * __uint_as_float(hv[u] << 16);
            acc1 += ex * __uint_as_float(hv[u] & 0xffff0000u);
        }
    }
    for (; i < end; i += 2) {
        int idx = i + half;
        if (idx < end) {
            int s = adjsrc[idx];
            float e = as[s] + adh;
            e = e > 0.f ? e : 0.2f * e;
            float ex = __expf(e);
            ssum += ex;
            unsigned int hv = act ? *reinterpret_cast<const unsigned int*>(&h2b[(size_t)s * 48 + l * 2]) : 0u;
            acc0 += ex * __uint_as_float(hv << 16);
            acc1 += ex * __uint_as_float(hv & 0xffff0000u);
        }
    }
    acc0 += __shfl_xor(acc0, 32, 64);
    acc1 += __shfl_xor(acc1, 32, 64);
    ssum += __shfl_xor(ssum, 32, 64);
    if (half == 0 && act) {
        float inv = 1.f / (ssum + 1e-16f);
        float2 o;
        o.x = acc0 * inv + b[2 * l];
        o.y = acc1 * inv + b[2 * l + 1];
        *reinterpret_cast<float2*>(&out[(size_t)n * NCLS + 2 * l]) = o;
    }
}

extern "C" void kernel_launch(void* const* d_in, const int* in_sizes, int n_in,
                              void* d_out, int out_size, void* d_ws, size_t ws_size,
                              hipStream_t stream) {
    const float* x      = (const float*)d_in[0];
    const int*   ei     = (const int*)d_in[1];
    const float* W1     = (const float*)d_in[2];
    const float* a_src1 = (const float*)d_in[3];
    const float* a_dst1 = (const float*)d_in[4];
    const float* b1     = (const float*)d_in[5];
    const float* W2     = (const float*)d_in[6];
    const float* a_src2 = (const float*)d_in[7];
    const float* a_dst2 = (const float*)d_in[8];
    const float* b2     = (const float*)d_in[9];
    float* out = (float*)d_out;

    const int N = in_sizes[0] / IN_DIM;
    const int E = in_sizes[1] / 2;
    const int* src = ei;
    const int* dst = ei + E;

    char* ws = (char*)d_ws;
    size_t off = 0;
    auto alloc = [&](size_t bytes) {
        void* p = ws + off;
        off = (off + bytes + 255) & ~(size_t)255;
        return p;
    };
    int*   deg    = (int*)alloc((size_t)N * 4);
    int*   excl   = (int*)alloc((size_t)N * 4);
    int*   bsum   = (int*)alloc((size_t)256 * 4);
    int*   rank   = (int*)alloc((size_t)E * 4);
    int*   offs   = (int*)alloc((size_t)(N + 1) * 4);
    int*   adjsrc = (int*)alloc((size_t)E * 4);
    unsigned short* W1tb  = (unsigned short*)alloc((size_t)256 * 256 * 2);
    unsigned short* W2tb  = (unsigned short*)alloc((size_t)64 * 256 * 2);
    unsigned short* Aw    = (unsigned short*)alloc((size_t)16 * 256 * 2);
    unsigned short* h1b   = (unsigned short*)alloc((size_t)N * HIDDEN * 2);
    unsigned short* out1b = (unsigned short*)alloc((size_t)N * HIDDEN * 2);
    unsigned short* h2b   = (unsigned short*)alloc((size_t)N * 48 * 2);
    float* as1    = (float*)alloc((size_t)N * HEADS * 4);
    float* ad1    = (float*)alloc((size_t)N * HEADS * 4);
    float* as2    = (float*)alloc((size_t)N * 4);
    float* ad2    = (float*)alloc((size_t)N * 4);

    const int nb = (N + 1023) / 1024;
    const int nhist = (E + 255) / 256;

    hipMemsetAsync(deg, 0, (size_t)N * 4, stream);
    histprep_kernel<<<dim3(nhist + 320), dim3(256), 0, stream>>>(dst, deg, rank, E,
                                                                 W1, W2, a_src1, a_dst1, a_src2, a_dst2,
                                                                 W1tb, W2tb, Aw, nhist);
    scan_blocks_kernel<<<dim3(nb), dim3(1024), 0, stream>>>(deg, excl, bsum, N);
    add_base_kernel<<<dim3((N + 256) / 256), dim3(256), 0, stream>>>(excl, bsum, offs, N, nb);
    fill_kernel<<<dim3((E + 255) / 256), dim3(256), 0, stream>>>(src, dst, rank, offs, adjsrc, E);

    gemm1_mfma<<<dim3((N + 127) / 128), dim3(512), 0, stream>>>(x, W1tb, Aw, h1b, as1, ad1, N);
    agg1_kernel<<<dim3((N + 3) / 4), dim3(256), 0, stream>>>(h1b, as1, ad1, offs, adjsrc, b1, out1b, N);

    gemm2_mfma<<<dim3((N + 127) / 128), dim3(512), 0, stream>>>(out1b, W2tb, h2b, as2, ad2, N);
    agg2_kernel<<<dim3((N + 3) / 4), dim3(256), 0, stream>>>(h2b, as2, ad2, offs, adjsrc, b2, out, N);
}